// Round 8
// baseline (201.332 us; speedup 1.0000x reference)
//
#include <hip/hip_runtime.h>
#include <hip/hip_bf16.h>
#include <hip/hip_cooperative_groups.h>

namespace cg = cooperative_groups;

typedef __hip_bfloat16 bf16;
typedef short bf16x8 __attribute__((ext_vector_type(8)));
typedef float f32x4 __attribute__((ext_vector_type(4)));

#define S_LEN 4096
#define NBATCH 2
#define EDIM 1024
#define DDIM 64
#define MROWS (NBATCH * S_LEN)   // 8192

#define GLOBAL_AS __attribute__((address_space(1)))
#define LDS_AS __attribute__((address_space(3)))

union frag_u { bf16x8 v; bf16 e[8]; };

// async 16B global -> LDS (dest wave-uniform; HW adds lane*16; src per-lane)
__device__ __forceinline__ void async_ld16(const void* gp, void* lp) {
  __builtin_amdgcn_global_load_lds((const GLOBAL_AS void*)gp,
                                   (LDS_AS void*)lp, 16, 0, 0);
}

// f32x8 -> split bf16 hi/lo fragments (x ~= hi + lo, rel err ~2^-17)
__device__ __forceinline__ void cvt_split(const float4& a, const float4& b,
                                          bf16x8& hi, bf16x8& lo) {
  float v[8] = {a.x, a.y, a.z, a.w, b.x, b.y, b.z, b.w};
  frag_u h, l;
#pragma unroll
  for (int e = 0; e < 8; e++) {
    bf16 hh = __float2bfloat16(v[e]);
    h.e[e] = hh;
    l.e[e] = __float2bfloat16(v[e] - __bfloat162float(hh));
  }
  hi = h.v;
  lo = l.v;
}

// ---------------------------------------------------------------------------
// ONE fused cooperative kernel. Grid 256 x 512. Phases:
//  P1 pack (blocks 0..47): W (f32 k-major) -> split-bf16 Wt[192 n][1024 k]
//     via LDS 64x65 transpose; block 0 zeroes Vsum.        --- grid.sync ---
//  P2 gemm: block = 32 rows x N=192 x K=1024. 8 waves = (mt 2) x (nh 4);
//     wave = 1 m-tile(16) x 3 n-tiles(16). 32 rounds of BK=32, double-
//     buffered global_load_lds staging (A 4KB f32 + Bh 12KB + Bl 12KB per
//     buffer; 2x28KB = 56KB LDS). Stage j+1 issues BEFORE compute j, so the
//     barrier's vmcnt drain overlaps compute. B LDS layout is read-order
//     contiguous (lane idx == 16B-unit idx -> m134-fast pattern).
//     Epilogue: bias + store qkv, V-column sums -> Vsum atomics.
//                                                          --- grid.sync ---
//  P3 attn: 32 queries/block, 2 per 32-lane half-wave. Full-row softmax
//     collapses to 5 window exps + (S-nvalid) background exp(0-m) terms;
//     background numerator = Vsum - sum(window V).
// MFMA f32_16x16x32_bf16, split-bf16 (xh*wh + xh*wl + xl*wh):
//   A-frag: A[m][k], m = lane&15, k = (lane>>4)*8 + e
//   B-frag: B[k][n], n = lane&15, k = (lane>>4)*8 + e
//   D:      D[m][n], m = (lane>>4)*4 + r, n = lane&15
// ---------------------------------------------------------------------------
__global__ __launch_bounds__(512, 2) void fused_kernel(
    const float* __restrict__ x, const float* __restrict__ Wq,
    const float* __restrict__ bq, const float* __restrict__ Wk,
    const float* __restrict__ bk, const float* __restrict__ Wv,
    const float* __restrict__ bv, bf16* __restrict__ Wt_hi,
    bf16* __restrict__ Wt_lo, float* __restrict__ qkv,
    float* __restrict__ Vsum, float* __restrict__ out) {
  __shared__ __align__(16) char lds[57344];   // 2 x 28KB gemm bufs; pack alias
  cg::grid_group grid = cg::this_grid();
  const int tid = threadIdx.x;
  const int lane = tid & 63;
  const int wave = tid >> 6;
  const int quad = lane >> 4;
  const int l16 = lane & 15;

  // ========== P1: weight pack ==========
  if (blockIdx.x < 48) {
    float* tile = (float*)lds;                // 64 x 65 f32 = 16.6 KB
    const int mat = blockIdx.x >> 4;
    const int kb = (blockIdx.x & 15) * 64;
    if (blockIdx.x == 0 && tid < NBATCH * DDIM) Vsum[tid] = 0.f;
    const float* W = (mat == 0) ? Wq : ((mat == 1) ? Wk : Wv);
#pragma unroll
    for (int i = 0; i < 2; i++) {
      int F = (i * 512 + tid) * 4;            // flat f32 idx in [0,4096)
      int k = F >> 6;
      int n4 = F & 63;
      float4 v = *(const float4*)(const void*)(W + (size_t)(kb + k) * 64 + n4);
      tile[(n4 + 0) * 65 + k] = v.x;
      tile[(n4 + 1) * 65 + k] = v.y;
      tile[(n4 + 2) * 65 + k] = v.z;
      tile[(n4 + 3) * 65 + k] = v.w;
    }
    __syncthreads();
    const int n = tid >> 3;
    const int kc = (tid & 7) * 8;
    frag_u h, l;
#pragma unroll
    for (int e = 0; e < 8; e++) {
      float v = tile[n * 65 + kc + e];
      bf16 hh = __float2bfloat16(v);
      h.e[e] = hh;
      l.e[e] = __float2bfloat16(v - __bfloat162float(hh));
    }
    size_t obase = (size_t)(mat * 64 + n) * EDIM + kb + kc;
    *(bf16x8*)(void*)(Wt_hi + obase) = h.v;
    *(bf16x8*)(void*)(Wt_lo + obase) = l.v;
  }
  grid.sync();

  // ========== P2: fused QKV GEMM ==========
  {
    const int rowBase = blockIdx.x * 32;
    const int mt = wave >> 2;                 // 16-row m-tile
    const int nh = wave & 3;                  // 3 n-tiles each

    // staging chunk assignment: wave w owns chunks {w, w+8, w+16, w+24(<28)}
    // chunk c: c<4 = A (32 rows x 32k f32), 4..15 = Bh, 16..27 = Bl.
    // All chunks are 1KB; LDS offset = c*1024 within the buffer.
    const char* gsrc[4];
    int gstride[4], ldoff[4];
    int nch = (wave < 4) ? 4 : 3;
#pragma unroll
    for (int s = 0; s < 4; s++) {
      int c = wave + s * 8;
      ldoff[s] = c * 1024;
      if (c < 4) {                            // A: unit=(gh*32+row), gh=c*2+(lane>>5)
        int gh = c * 2 + (lane >> 5);
        int row = lane & 31;
        gsrc[s] = (const char*)(x + (size_t)(rowBase + row) * EDIM + gh * 4);
        gstride[s] = 128;                     // 32 f32 per round
      } else if (c < 16) {                    // Bh: chunk cb = n-tile cb
        int cb = c - 4;
        int nn = cb * 16 + l16;
        gsrc[s] = (const char*)(Wt_hi + (size_t)nn * EDIM + quad * 8);
        gstride[s] = 64;                      // 32 bf16 per round
      } else {
        int cb = c - 16;
        int nn = cb * 16 + l16;
        gsrc[s] = (const char*)(Wt_lo + (size_t)nn * EDIM + quad * 8);
        gstride[s] = 64;
      }
    }

    f32x4 acc[3];
#pragma unroll
    for (int t = 0; t < 3; t++) acc[t] = (f32x4){0.f, 0.f, 0.f, 0.f};

    // prologue: stage round 0 into buf 0
#pragma unroll
    for (int s = 0; s < 4; s++)
      if (s < nch) async_ld16(gsrc[s], lds + ldoff[s]);
    __syncthreads();

    for (int j = 0; j < 32; j++) {
      const int b = j & 1;
      if (j + 1 < 32) {                       // stage j+1 into other buffer
        char* nb = lds + (1 - b) * 28672;
#pragma unroll
        for (int s = 0; s < 4; s++)
          if (s < nch)
            async_ld16(gsrc[s] + (size_t)(j + 1) * gstride[s], nb + ldoff[s]);
      }
      // compute round j from buf b
      const float* Ab = (const float*)(lds + b * 28672);
      const bf16* Bhb = (const bf16*)(lds + b * 28672 + 4096);
      const bf16* Blb = (const bf16*)(lds + b * 28672 + 16384);
      const float* ap = Ab + quad * 256 + (mt * 16 + l16) * 4;
      float4 a0 = *(const float4*)(const void*)ap;
      float4 a1 = *(const float4*)(const void*)(ap + 128);
      bf16x8 ah, al;
      cvt_split(a0, a1, ah, al);
#pragma unroll
      for (int t = 0; t < 3; t++) {
        int nt = nh * 3 + t;
        bf16x8 bh = *(const bf16x8*)(const void*)(Bhb + nt * 512 + lane * 8);
        bf16x8 bl = *(const bf16x8*)(const void*)(Blb + nt * 512 + lane * 8);
        acc[t] = __builtin_amdgcn_mfma_f32_16x16x32_bf16(ah, bh, acc[t], 0, 0, 0);
        acc[t] = __builtin_amdgcn_mfma_f32_16x16x32_bf16(ah, bl, acc[t], 0, 0, 0);
        acc[t] = __builtin_amdgcn_mfma_f32_16x16x32_bf16(al, bh, acc[t], 0, 0, 0);
      }
      __syncthreads();                        // drains staging j+1 too
    }

    // epilogue: bias + store + V column sums
    const int bb = rowBase >> 12;
#pragma unroll
    for (int t = 0; t < 3; t++) {
      int nt = nh * 3 + t;
      int n = nt * 16 + l16;
      int mat = n >> 6;
      int col = n & 63;
      float bias = (mat == 0) ? bq[col] : ((mat == 1) ? bk[col] : bv[col]);
      float* dst = qkv + (size_t)mat * MROWS * DDIM +
                   (size_t)(rowBase + mt * 16 + quad * 4) * DDIM + col;
      float vs = 0.f;
#pragma unroll
      for (int r = 0; r < 4; r++) {
        float val = acc[t][r] + bias;
        dst[r * DDIM] = val;
        vs += val;
      }
      if (nt >= 8) {                          // V tiles -> Vsum
        vs += __shfl_xor(vs, 16, 64);
        vs += __shfl_xor(vs, 32, 64);
        if (quad == 0) atomicAdd(&Vsum[bb * DDIM + (n - 128)], vs);
      }
    }
  }
  grid.sync();

  // ========== P3: attention ==========
  {
    const float* Qf = qkv;
    const float* Kf = qkv + (size_t)MROWS * DDIM;
    const float* Vf = qkv + (size_t)2 * MROWS * DDIM;
    int l = tid & 31;
#pragma unroll
    for (int c = 0; c < 2; c++) {
      int qidx = blockIdx.x * 32 + c * 16 + (tid >> 5);
      int b = qidx >> 12;
      int i = qidx & 4095;

      float2 q = *(const float2*)(const void*)(Qf + (size_t)qidx * DDIM + 2 * l);
      float sc[5];
      float2 vv[5];
      bool val[5];
#pragma unroll
      for (int w = 0; w < 5; w++) {
        int j = i + 2 * w - 4;                // DIL*(w - WIN/2), DIL=2
        val[w] = (j >= 0) && (j < S_LEN);
        int jj = val[w] ? j : i;
        size_t off = (size_t)(b * S_LEN + jj) * DDIM + 2 * l;
        float2 kk = *(const float2*)(const void*)(Kf + off);
        vv[w] = *(const float2*)(const void*)(Vf + off);
        float p = q.x * kk.x + q.y * kk.y;
#pragma unroll
        for (int d = 1; d < 32; d <<= 1) p += __shfl_xor(p, d, 64);
        sc[w] = p;
      }

      float mx = 0.f;                         // background score 0 in the max
#pragma unroll
      for (int w = 0; w < 5; w++)
        if (val[w]) mx = fmaxf(mx, sc[w]);

      float denom = 0.f;
      float2 accv = {0.f, 0.f}, vsel = {0.f, 0.f};
      int nval = 0;
#pragma unroll
      for (int w = 0; w < 5; w++)
        if (val[w]) {
          float pexp = __expf(sc[w] - mx);
          denom += pexp;
          accv.x += pexp * vv[w].x;
          accv.y += pexp * vv[w].y;
          vsel.x += vv[w].x;
          vsel.y += vv[w].y;
          nval++;
        }
      float pbg = __expf(-mx);
      denom += pbg * (float)(S_LEN - nval);
      float2 vsm = *(const float2*)(const void*)(Vsum + b * DDIM + 2 * l);
      accv.x += pbg * (vsm.x - vsel.x);
      accv.y += pbg * (vsm.y - vsel.y);

      float2 o = {accv.x / denom, accv.y / denom};
      *(float2*)(void*)(out + (size_t)qidx * DDIM + 2 * l) = o;
    }
  }
}

// ---------------------------------------------------------------------------
extern "C" void kernel_launch(void* const* d_in, const int* in_sizes, int n_in,
                              void* d_out, int out_size, void* d_ws,
                              size_t ws_size, hipStream_t stream) {
  const float* x = (const float*)d_in[0];
  const float* Wq = (const float*)d_in[1];
  const float* bq = (const float*)d_in[2];
  const float* Wk = (const float*)d_in[3];
  const float* bk = (const float*)d_in[4];
  const float* Wv = (const float*)d_in[5];
  const float* bv = (const float*)d_in[6];
  float* out = (float*)d_out;

  char* ws = (char*)d_ws;
  bf16* Wt_hi = (bf16*)ws;                    // 393216 B
  bf16* Wt_lo = (bf16*)(ws + 393216);         // 393216 B
  float* qkv = (float*)(ws + 786432);         // 3*8192*64*4 = 6291456 B
  float* Vsum = (float*)(ws + 786432 + 6291456);  // 512 B
  // total workspace ~7.1 MB

  void* args[] = {&x, &Wq, &bq, &Wk, &bk, &Wv, &bv,
                  &Wt_hi, &Wt_lo, &qkv, &Vsum, &out};
  hipLaunchCooperativeKernel((const void*)fused_kernel, dim3(256), dim3(512),
                             args, 0, stream);
}

// Round 9
// 117.760 us; speedup vs baseline: 1.7097x; 1.7097x over previous
//
#include <hip/hip_runtime.h>
#include <hip/hip_bf16.h>

typedef __hip_bfloat16 bf16;
typedef short bf16x8 __attribute__((ext_vector_type(8)));
typedef float f32x4 __attribute__((ext_vector_type(4)));

#define S_LEN 4096
#define NBATCH 2
#define EDIM 1024
#define DDIM 64
#define MROWS (NBATCH * S_LEN)   // 8192

#define GLOBAL_AS __attribute__((address_space(1)))
#define LDS_AS __attribute__((address_space(3)))

union frag_u { bf16x8 v; bf16 e[8]; };

// async 16B global -> LDS (dest wave-uniform; HW adds lane*16; src per-lane)
__device__ __forceinline__ void async_ld16(const void* gp, void* lp) {
  __builtin_amdgcn_global_load_lds((const GLOBAL_AS void*)gp,
                                   (LDS_AS void*)lp, 16, 0, 0);
}

// f32x8 -> split bf16 hi/lo fragments (x ~= hi + lo, rel err ~2^-17)
__device__ __forceinline__ void cvt_split(const float4& a, const float4& b,
                                          bf16x8& hi, bf16x8& lo) {
  float v[8] = {a.x, a.y, a.z, a.w, b.x, b.y, b.z, b.w};
  frag_u h, l;
#pragma unroll
  for (int e = 0; e < 8; e++) {
    bf16 hh = __float2bfloat16(v[e]);
    h.e[e] = hh;
    l.e[e] = __float2bfloat16(v[e] - __bfloat162float(hh));
  }
  hi = h.v;
  lo = l.v;
}

// ---------------------------------------------------------------------------
// Pack weights (f32, k-major [1024][64]) -> split-bf16 in ROUND-MAJOR
// STAGING ORDER: Wt2[j=0..31][unit u=0..767][8 bf16], where round j covers
// k in [j*32, j*32+32). Unit for (n, kk): n2 = n>>1, pp = (n&1)*4 + (kk>>3),
// sp = pp ^ (n2 & 7)  (XOR swizzle -> 2-way-free LDS reads),
// u = n2*8 + sp, elem = kk&7.  A round block = 12288 B, byte-identical to
// its LDS image, so gemm B staging is a pure contiguous memcpy.
// Grid 48 = 3 mats x 16 k-blocks; LDS 64x65 transpose keeps reads coalesced.
// Block 0 zeroes Vsum.
// ---------------------------------------------------------------------------
__global__ __launch_bounds__(256) void pack_w_kernel(
    const float* __restrict__ Wq, const float* __restrict__ Wk,
    const float* __restrict__ Wv, bf16* __restrict__ Wt2_hi,
    bf16* __restrict__ Wt2_lo, float* __restrict__ Vsum) {
  __shared__ float tile[64 * 65];
  const int mat = blockIdx.x >> 4;
  const int kb = blockIdx.x & 15;             // 64-k block -> rounds 2kb,2kb+1
  const int t = threadIdx.x;
  if (blockIdx.x == 0 && t < NBATCH * DDIM) Vsum[t] = 0.f;
  const float* W = (mat == 0) ? Wq : ((mat == 1) ? Wk : Wv);

#pragma unroll
  for (int i = 0; i < 4; i++) {
    int F = (i * 256 + t) * 4;                // flat f32 idx in [0,4096)
    int k = F >> 6;
    int n4 = F & 63;
    float4 v = *(const float4*)(const void*)(W + (size_t)(kb * 64 + k) * 64 + n4);
    tile[(n4 + 0) * 65 + k] = v.x;
    tile[(n4 + 1) * 65 + k] = v.y;
    tile[(n4 + 2) * 65 + k] = v.z;
    tile[(n4 + 3) * 65 + k] = v.w;
  }
  __syncthreads();

  // 512 units (hi+lo written together): nl, j_half, pp_k
#pragma unroll
  for (int it = 0; it < 2; it++) {
    int uidx = it * 256 + t;
    int nl = uidx >> 3;
    int j_half = (uidx >> 2) & 1;
    int pp_k = uidx & 3;
    int ng = mat * 64 + nl;                   // global n in [0,192)
    int n2 = ng >> 1;
    int sp = ((ng & 1) * 4 + pp_k) ^ (n2 & 7);
    int unit = n2 * 8 + sp;
    int j = kb * 2 + j_half;
    frag_u h, l;
#pragma unroll
    for (int e = 0; e < 8; e++) {
      float v = tile[nl * 65 + j_half * 32 + pp_k * 8 + e];
      bf16 hh = __float2bfloat16(v);
      h.e[e] = hh;
      l.e[e] = __float2bfloat16(v - __bfloat162float(hh));
    }
    size_t ob = (size_t)j * 6144 + unit * 8;
    *(bf16x8*)(void*)(Wt2_hi + ob) = h.v;
    *(bf16x8*)(void*)(Wt2_lo + ob) = l.v;
  }
}

// ---------------------------------------------------------------------------
// Fused QKV GEMM v5 — coalesced staging (the r3-r8 disease: global loads
// derived from fragment layout -> 64-line scatter per instruction).
// M=8192, K=1024, N=192. Grid 256 x 512 (8 waves, 1 block/CU).
// Block = 32 rows x N=192 x K=1024; 32 rounds of BK=32, double-buffered.
// Per round 28 KB staged via global_load_lds, ALL memory-contiguous:
//   chunks 0-3   A: 8 rows x 128B segments, lane=(row<<3)|p, src part
//                p ^ (row&7)  -> LDS pos (row*8 + (part^(row&7)))*16B
//   chunks 4-15  Bh: byte-copy of Wt2_hi round block (pre-swizzled)
//   chunks 16-27 Bl: byte-copy of Wt2_lo round block
// Fragment reads (both 2-way bank conflict = free):
//   A: lane(l16,quad) float4 @ (l16*8 + ((quad*2+s)^(l16&7)))*16, s=0,1
//   B: lane(l16,quad) b128  @ ((nt*8+(l16>>1))*8 + (((l16&1)*4+quad)^((l16>>1)&7)))*16
// Wave (mt,nh): mt = 16-row half, nh -> n-tiles nh*3..nh*3+2; 9 MFMA/round.
// Epilogue: bias + store qkv; V-column sums -> Vsum atomics.
// MFMA f32_16x16x32_bf16 split-bf16 (xh*wh + xh*wl + xl*wh):
//   A[m][k]: m=lane&15, k=(lane>>4)*8+e | B[k][n]: n=lane&15, k=(lane>>4)*8+e
//   D[m][n]: m=(lane>>4)*4+r, n=lane&15
// ---------------------------------------------------------------------------
__global__ __launch_bounds__(512, 2) void qkv_gemm_kernel(
    const float* __restrict__ x, const bf16* __restrict__ Wt2_hi,
    const bf16* __restrict__ Wt2_lo, const float* __restrict__ bq,
    const float* __restrict__ bk, const float* __restrict__ bv,
    float* __restrict__ qkv, float* __restrict__ Vsum) {
  __shared__ __align__(16) char lds[57344];   // 2 x 28 KB
  const int tid = threadIdx.x;
  const int lane = tid & 63;
  const int wave = tid >> 6;
  const int quad = lane >> 4;
  const int l16 = lane & 15;
  const int mt = wave >> 2;
  const int nh = wave & 3;
  const int rowBase = blockIdx.x * 32;

  // staging chunk assignment: wave w owns chunks {w, w+8, w+16, w+24(<28)}
  const char* gsrc[4];
  int gstride[4], ldoff[4];
  const int nch = (wave < 4) ? 4 : 3;
#pragma unroll
  for (int s = 0; s < 4; s++) {
    int c = wave + s * 8;
    ldoff[s] = c * 1024;
    if (c < 4) {                              // A: rows c*8..c*8+7
      int rin = lane >> 3;                    // row within chunk (=(row&7))
      int part = (lane & 7) ^ rin;            // source 16B part (swizzled)
      gsrc[s] = (const char*)(x + (size_t)(rowBase + c * 8 + rin) * EDIM +
                              part * 4);
      gstride[s] = 128;                       // 32 f32 per round
    } else if (c < 16) {
      gsrc[s] = (const char*)Wt2_hi + (c - 4) * 1024 + lane * 16;
      gstride[s] = 12288;                     // one round block
    } else {
      gsrc[s] = (const char*)Wt2_lo + (c - 16) * 1024 + lane * 16;
      gstride[s] = 12288;
    }
  }

  f32x4 acc[3];
#pragma unroll
  for (int t = 0; t < 3; t++) acc[t] = (f32x4){0.f, 0.f, 0.f, 0.f};

  // prologue: stage round 0 into buf 0
#pragma unroll
  for (int s = 0; s < 4; s++)
    if (s < nch) async_ld16(gsrc[s], lds + ldoff[s]);
  __syncthreads();

  const int arow = mt * 16 + l16;             // row&7 == l16&7 (mt*16%8==0)
  const int asp0 = (quad * 2) ^ (l16 & 7);
  for (int j = 0; j < 32; j++) {
    const int b = j & 1;
    if (j + 1 < 32) {                         // stage j+1 into other buffer
      char* nb = lds + (1 - b) * 28672;
#pragma unroll
      for (int s = 0; s < 4; s++)
        if (s < nch)
          async_ld16(gsrc[s] + (size_t)(j + 1) * gstride[s], nb + ldoff[s]);
    }
    const char* Ab = lds + b * 28672;
    const bf16* Bhb = (const bf16*)(lds + b * 28672 + 4096);
    const bf16* Blb = (const bf16*)(lds + b * 28672 + 16384);
    float4 a0 = *(const float4*)(const void*)(Ab + (arow * 8 + asp0) * 16);
    float4 a1 = *(const float4*)(const void*)(Ab + (arow * 8 + (asp0 ^ 1)) * 16);
    bf16x8 ah, al;
    cvt_split(a0, a1, ah, al);
#pragma unroll
    for (int t = 0; t < 3; t++) {
      int nt = nh * 3 + t;
      int n2 = nt * 8 + (l16 >> 1);
      int sp = (((l16 & 1) * 4) + quad) ^ ((l16 >> 1) & 7);
      int uoff = (n2 * 8 + sp) * 8;           // bf16 offset
      bf16x8 bh = *(const bf16x8*)(const void*)(Bhb + uoff);
      bf16x8 bl = *(const bf16x8*)(const void*)(Blb + uoff);
      acc[t] = __builtin_amdgcn_mfma_f32_16x16x32_bf16(ah, bh, acc[t], 0, 0, 0);
      acc[t] = __builtin_amdgcn_mfma_f32_16x16x32_bf16(ah, bl, acc[t], 0, 0, 0);
      acc[t] = __builtin_amdgcn_mfma_f32_16x16x32_bf16(al, bh, acc[t], 0, 0, 0);
    }
    __syncthreads();                          // drains staging j+1 too
  }

  // epilogue: bias + store + V column sums
  const int bb = rowBase >> 12;
#pragma unroll
  for (int t = 0; t < 3; t++) {
    int nt = nh * 3 + t;
    int n = nt * 16 + l16;
    int mat = n >> 6;
    int col = n & 63;
    float bias = (mat == 0) ? bq[col] : ((mat == 1) ? bk[col] : bv[col]);
    float* dst = qkv + (size_t)mat * MROWS * DDIM +
                 (size_t)(rowBase + mt * 16 + quad * 4) * DDIM + col;
    float vs = 0.f;
#pragma unroll
    for (int r = 0; r < 4; r++) {
      float val = acc[t][r] + bias;
      dst[r * DDIM] = val;
      vs += val;
    }
    if (nt >= 8) {                            // V tiles -> Vsum
      vs += __shfl_xor(vs, 16, 64);
      vs += __shfl_xor(vs, 32, 64);
      if (quad == 0) atomicAdd(&Vsum[bb * DDIM + (n - 128)], vs);
    }
  }
}

// ---------------------------------------------------------------------------
// Attention: 2 queries per wave, 32 lanes each, lane owns a float2 dim-pair.
// Full-row softmax collapses to: 5 window exps + (S - nvalid) background
// exp(0-m) terms; background numerator = Vsum - sum(window V).
// ---------------------------------------------------------------------------
__global__ __launch_bounds__(256) void attn_kernel(
    const float* __restrict__ qkv, const float* __restrict__ Vsum,
    float* __restrict__ out) {
  const float* Qf = qkv;
  const float* Kf = qkv + (size_t)MROWS * DDIM;
  const float* Vf = qkv + (size_t)2 * MROWS * DDIM;
  int l = threadIdx.x & 31;
  int qidx = blockIdx.x * 8 + (threadIdx.x >> 5);
  int b = qidx >> 12;
  int i = qidx & 4095;

  float2 q = *(const float2*)(const void*)(Qf + (size_t)qidx * DDIM + 2 * l);
  float sc[5];
  float2 vv[5];
  bool val[5];
#pragma unroll
  for (int w = 0; w < 5; w++) {
    int j = i + 2 * w - 4;                    // DIL*(w - WIN/2), DIL=2
    val[w] = (j >= 0) && (j < S_LEN);
    int jj = val[w] ? j : i;
    size_t off = (size_t)(b * S_LEN + jj) * DDIM + 2 * l;
    float2 kk = *(const float2*)(const void*)(Kf + off);
    vv[w] = *(const float2*)(const void*)(Vf + off);
    float p = q.x * kk.x + q.y * kk.y;
#pragma unroll
    for (int d = 1; d < 32; d <<= 1) p += __shfl_xor(p, d, 64);
    sc[w] = p;
  }

  float mx = 0.f;                             // background score 0 in the max
#pragma unroll
  for (int w = 0; w < 5; w++)
    if (val[w]) mx = fmaxf(mx, sc[w]);

  float denom = 0.f;
  float2 accv = {0.f, 0.f}, vsel = {0.f, 0.f};
  int nval = 0;
#pragma unroll
  for (int w = 0; w < 5; w++)
    if (val[w]) {
      float pexp = __expf(sc[w] - mx);
      denom += pexp;
      accv.x += pexp * vv[w].x;
      accv.y += pexp * vv[w].y;
      vsel.x += vv[w].x;
      vsel.y += vv[w].y;
      nval++;
    }
  float pbg = __expf(-mx);
  denom += pbg * (float)(S_LEN - nval);
  float2 vsm = *(const float2*)(const void*)(Vsum + b * DDIM + 2 * l);
  accv.x += pbg * (vsm.x - vsel.x);
  accv.y += pbg * (vsm.y - vsel.y);

  float2 o = {accv.x / denom, accv.y / denom};
  *(float2*)(void*)(out + (size_t)qidx * DDIM + 2 * l) = o;
}

// ---------------------------------------------------------------------------
extern "C" void kernel_launch(void* const* d_in, const int* in_sizes, int n_in,
                              void* d_out, int out_size, void* d_ws,
                              size_t ws_size, hipStream_t stream) {
  const float* x = (const float*)d_in[0];
  const float* Wq = (const float*)d_in[1];
  const float* bq = (const float*)d_in[2];
  const float* Wk = (const float*)d_in[3];
  const float* bk = (const float*)d_in[4];
  const float* Wv = (const float*)d_in[5];
  const float* bv = (const float*)d_in[6];
  float* out = (float*)d_out;

  char* ws = (char*)d_ws;
  bf16* Wt2_hi = (bf16*)ws;                   // 32*6144*2 = 393216 B
  bf16* Wt2_lo = (bf16*)(ws + 393216);        // 393216 B
  float* qkv = (float*)(ws + 786432);         // 3*8192*64*4 = 6291456 B
  float* Vsum = (float*)(ws + 786432 + 6291456);  // 512 B
  // total workspace ~7.1 MB

  hipLaunchKernelGGL(pack_w_kernel, dim3(48), dim3(256), 0, stream, Wq, Wk, Wv,
                     Wt2_hi, Wt2_lo, Vsum);
  hipLaunchKernelGGL(qkv_gemm_kernel, dim3(256), dim3(512), 0, stream, x,
                     Wt2_hi, Wt2_lo, bq, bk, bv, qkv, Vsum);
  hipLaunchKernelGGL(attn_kernel, dim3(1024), dim3(256), 0, stream, qkv, Vsum,
                     out);
}